// Round 15
// baseline (160.097 us; speedup 1.0000x reference)
//
#include <hip/hip_runtime.h>
#include <hip/hip_bf16.h>
#include <hip/hip_fp16.h>
#include <math.h>

// AutoCorrelation (Autoformer). B=16, L=2048, H=8, E=64, fp32.
// Round 15: transpose moved to the consumer. pack = pure grid-stride
// streaming convert (q,k rows -> z rows, [t][cq] layout, no transpose) --
// structurally the copy ubench. fft staging does the transpose by reading
// z at 16B/lane, 2KB stride, from the L2/L3-resident z, with the r4-proven
// XCD swizzle (4 line-sharing cg-blocks -> same XCD). FFT compute, reduce,
// ifft, topk, aggregate byte-identical to validated r14.

#define B_ 16
#define L_ 2048
#define H_ 8
#define E_ 64
#define K_ 7
#define RS_ 2178          // region stride in uint2 (8B) units; sg(2047)=2174 < RS_

// ---------- workspace layout ----------
#define Z_OFF    0ull                              // fp16 z[b][t][cq]: 64 MiB
#define PART_OFF 67108864ull                       // float2[2048][2048] = 32 MiB
#define S_OFF    (PART_OFF + 33554432ull)          // float2[16][2048] = 256 KiB
#define MV_OFF   (S_OFF + 262144ull)               // float [B][L]
#define TK_OFF   (MV_OFF + 131072ull)              // int[7]
#define W_OFF    (TK_OFF + 64ull)                  // float[16][7]

// ---------- fp32 complex helpers (ifft/twiddle gen) ----------
__device__ __forceinline__ float2 cadd(float2 a, float2 b) { return make_float2(a.x + b.x, a.y + b.y); }
__device__ __forceinline__ float2 csub(float2 a, float2 b) { return make_float2(a.x - b.x, a.y - b.y); }
__device__ __forceinline__ float2 cmul(float2 a, float2 b) {
  return make_float2(fmaf(a.x, b.x, -a.y * b.y), fmaf(a.x, b.y, a.y * b.x));
}
__device__ __forceinline__ float2 cis(float ang) { float s, c; sincosf(ang, &s, &c); return make_float2(c, s); }

template<int S> __device__ __forceinline__ float2 rot90(float2 z) {
  return (S < 0) ? make_float2(z.y, -z.x) : make_float2(-z.y, z.x);
}
template<int S> __device__ __forceinline__ void dft4(float2& a, float2& b, float2& c, float2& d) {
  float2 t0 = cadd(a, c), t1 = csub(a, c), t2 = cadd(b, d), t3 = rot90<S>(csub(b, d));
  a = cadd(t0, t2); c = csub(t0, t2); b = cadd(t1, t3); d = csub(t1, t3);
}
template<int S> __device__ __forceinline__ void dft8(float2 v[8]) {
  const float RT = 0.70710678118654752f;
  const float SR = (S < 0) ? -RT : RT;
  float2 a0 = cadd(v[0], v[4]), a1 = cadd(v[1], v[5]), a2 = cadd(v[2], v[6]), a3 = cadd(v[3], v[7]);
  float2 b0 = csub(v[0], v[4]), b1 = csub(v[1], v[5]), b2 = csub(v[2], v[6]), b3 = csub(v[3], v[7]);
  b1 = cmul(b1, make_float2(RT, SR));
  b2 = rot90<S>(b2);
  b3 = cmul(b3, make_float2(-RT, SR));
  dft4<S>(a0, a1, a2, a3);
  dft4<S>(b0, b1, b2, b3);
  v[0] = a0; v[2] = a1; v[4] = a2; v[6] = a3;
  v[1] = b0; v[3] = b1; v[5] = b2; v[7] = b3;
}
// padded index: +1 element per 16 (<=2-way across all stage patterns)
__device__ __forceinline__ int sg(int e) { return e + (e >> 4); }

// ---------- packed-fp16 complex (channel pair per __half2 lane-slot) ----------
struct hc { __half2 re, im; };
__device__ __forceinline__ hc hcadd(hc a, hc b) { return { __hadd2(a.re, b.re), __hadd2(a.im, b.im) }; }
__device__ __forceinline__ hc hcsub(hc a, hc b) { return { __hsub2(a.re, b.re), __hsub2(a.im, b.im) }; }
template<int S> __device__ __forceinline__ hc hrot90(hc z) {       // *(-i) fwd
  hc r; if (S < 0) { r.re = z.im; r.im = __hneg2(z.re); } else { r.re = __hneg2(z.im); r.im = z.re; }
  return r;
}
__device__ __forceinline__ hc hcmul(hc v, __half2 wre, __half2 wim) {
  hc r;
  r.re = __hsub2(__hmul2(v.re, wre), __hmul2(v.im, wim));
  r.im = __hfma2(v.re, wim, __hmul2(v.im, wre));
  return r;
}
template<int S> __device__ __forceinline__ void hdft4(hc& a, hc& b, hc& c, hc& d) {
  hc t0 = hcadd(a, c), t1 = hcsub(a, c), t2 = hcadd(b, d), t3 = hrot90<S>(hcsub(b, d));
  a = hcadd(t0, t2); c = hcsub(t0, t2); b = hcadd(t1, t3); d = hcsub(t1, t3);
}
template<int S> __device__ __forceinline__ void hdft8(hc v[8]) {
  const float RT = 0.70710678118654752f;
  __half2 rt  = __float2half2_rn(RT);
  __half2 sr  = __float2half2_rn((S < 0) ? -RT : RT);
  __half2 nrt = __float2half2_rn(-RT);
  hc a0 = hcadd(v[0], v[4]), a1 = hcadd(v[1], v[5]), a2 = hcadd(v[2], v[6]), a3 = hcadd(v[3], v[7]);
  hc b0 = hcsub(v[0], v[4]), b1 = hcsub(v[1], v[5]), b2 = hcsub(v[2], v[6]), b3 = hcsub(v[3], v[7]);
  b1 = hcmul(b1, rt, sr);
  b2 = hrot90<S>(b2);
  b3 = hcmul(b3, nrt, sr);
  hdft4<S>(a0, a1, a2, a3);
  hdft4<S>(b0, b1, b2, b3);
  v[0] = a0; v[2] = a1; v[4] = a2; v[6] = a3;
  v[1] = b0; v[3] = b1; v[5] = b2; v[7] = b3;
}
__device__ __forceinline__ __half2 u2h(unsigned u) { return __builtin_bit_cast(__half2, u); }
__device__ __forceinline__ unsigned h2u(__half2 h) { return __builtin_bit_cast(unsigned, h); }

// ---------- kernel P: pure streaming convert q,k -> z[b][t][cq] ----------
// No transpose, no LDS, no barrier. f4 at (b,t,cq) = [re01,im01,re23,im23]
// with re01 = half2(q[4cq],q[4cq+1]), im01 = half2(k[4cq],k[4cq+1]), etc.
// 4,194,304 f4 total; 2048 blocks x 256 threads x 8 strided iterations.
__global__ __launch_bounds__(256) void pack_kernel(
    const float* __restrict__ q, const float* __restrict__ k,
    float4* __restrict__ z) {
  const float4* q4 = (const float4*)q;
  const float4* k4 = (const float4*)k;
  int idx0 = blockIdx.x * 256 + threadIdx.x;
#pragma unroll
  for (int it = 0; it < 8; ++it) {
    int idx = idx0 + it * (2048 * 256);
    float4 qv = q4[idx];
    float4 kv = k4[idx];
    float4 pk;
    ((__half2*)&pk)[0] = __float22half2_rn(make_float2(qv.x, qv.y));  // re01
    ((__half2*)&pk)[1] = __float22half2_rn(make_float2(kv.x, kv.y));  // im01
    ((__half2*)&pk)[2] = __float22half2_rn(make_float2(qv.z, qv.w));  // re23
    ((__half2*)&pk)[3] = __float22half2_rn(make_float2(kv.z, kv.w));  // im23
    z[idx] = pk;
  }
}

// ---------- kernel F: packed-fp16 radix-8/8/8/4 DIF FFT + freq product ----------
// Block (b, cg): channels 4cg..4cg+3 as 2 packed pairs processed TOGETHER
// (dual register sets, one barrier per stage). 256 threads; 2 LDS regions of
// RS_ uint2. Staging does the TRANSPOSE: 16B/lane at 2KB stride from the
// L2/L3-resident z; XCD swizzle co-locates the 4 line-sharing cg-blocks.
// Digit-reversed storage pos=256k1+32k2+4k3+k4, f=k1+8k2+64k3+512k4.
__global__ __launch_bounds__(256, 4) void fft_corr_kernel(
    const float4* __restrict__ z, float2* __restrict__ part) {
  extern __shared__ uint2 dbuf[];         // 2 regions x RS_ uint2 = 34848 B
  int t = threadIdx.x;
  int j2 = t & 31, j3 = t & 3;
  // XCD swizzle (r4-proven): the 4 logical blocks sharing each 64B z line
  // (consecutive cg quad) map to the same physical p&7 (same XCD) and are
  // dispatched 8 apart.
  int pphys = blockIdx.x;
  int i = pphys >> 3, x = pphys & 7;
  int l = ((i >> 2) << 5) | (x << 2) | (i & 3);   // bijective on [0,2048)
  int cg = l & 127, b = l >> 7;
  const float4* zb = z + (size_t)b * L_ * 128;

  // ---- staging + transpose: tau = it*256+t, 16B at 2KB stride (L2-served)
#pragma unroll
  for (int it = 0; it < 8; ++it) {
    int tau = it * 256 + t;
    float4 pk = zb[(size_t)tau * 128 + cg];
    int sp = sg(tau);
    dbuf[sp]       = make_uint2(__float_as_uint(pk.x), __float_as_uint(pk.y));
    dbuf[RS_ + sp] = make_uint2(__float_as_uint(pk.z), __float_as_uint(pk.w));
  }

  // twiddles: fp32 iterative chains -> broadcast half2
  __half2 t1re[7], t1im[7], t2re[7], t2im[7], t3re[7], t3im[7];
  {
    float2 w1 = cis(-6.283185307179586f * (float)t  / 2048.0f);
    float2 w2 = cis(-6.283185307179586f * (float)j2 / 256.0f);
    float2 w3 = cis(-6.283185307179586f * (float)j3 / 32.0f);
    float2 a1 = w1, a2 = w2, a3 = w3;
#pragma unroll
    for (int kk = 0; kk < 7; ++kk) {
      t1re[kk] = __float2half2_rn(a1.x); t1im[kk] = __float2half2_rn(a1.y);
      t2re[kk] = __float2half2_rn(a2.x); t2im[kk] = __float2half2_rn(a2.y);
      t3re[kk] = __float2half2_rn(a3.x); t3im[kk] = __float2half2_rn(a3.y);
      a1 = cmul(a1, w1); a2 = cmul(a2, w2); a3 = cmul(a3, w3);
    }
  }
  int base2 = (t >> 5) * 256 + j2;
  int base3 = (t >> 2) * 32 + j3;
  uint2* R0 = dbuf;
  uint2* R1 = dbuf + RS_;
  hc v0[8], v1[8];
  __syncthreads();                        // staging visible

  // ---- stage 1 (M=2048), both regions, in-place per thread
#pragma unroll
  for (int m = 0; m < 8; ++m) {
    uint2 u = R0[sg(t + 256 * m)]; v0[m].re = u2h(u.x); v0[m].im = u2h(u.y);
    u = R1[sg(t + 256 * m)];       v1[m].re = u2h(u.x); v1[m].im = u2h(u.y);
  }
  hdft8<-1>(v0); hdft8<-1>(v1);
#pragma unroll
  for (int kk = 1; kk < 8; ++kk) {
    v0[kk] = hcmul(v0[kk], t1re[kk - 1], t1im[kk - 1]);
    v1[kk] = hcmul(v1[kk], t1re[kk - 1], t1im[kk - 1]);
  }
#pragma unroll
  for (int kk = 0; kk < 8; ++kk) {
    R0[sg(t + 256 * kk)] = make_uint2(h2u(v0[kk].re), h2u(v0[kk].im));
    R1[sg(t + 256 * kk)] = make_uint2(h2u(v1[kk].re), h2u(v1[kk].im));
  }
  __syncthreads();
  // ---- stage 2 (M=256)
#pragma unroll
  for (int m = 0; m < 8; ++m) {
    uint2 u = R0[sg(base2 + 32 * m)]; v0[m].re = u2h(u.x); v0[m].im = u2h(u.y);
    u = R1[sg(base2 + 32 * m)];       v1[m].re = u2h(u.x); v1[m].im = u2h(u.y);
  }
  hdft8<-1>(v0); hdft8<-1>(v1);
#pragma unroll
  for (int kk = 1; kk < 8; ++kk) {
    v0[kk] = hcmul(v0[kk], t2re[kk - 1], t2im[kk - 1]);
    v1[kk] = hcmul(v1[kk], t2re[kk - 1], t2im[kk - 1]);
  }
#pragma unroll
  for (int kk = 0; kk < 8; ++kk) {
    R0[sg(base2 + 32 * kk)] = make_uint2(h2u(v0[kk].re), h2u(v0[kk].im));
    R1[sg(base2 + 32 * kk)] = make_uint2(h2u(v1[kk].re), h2u(v1[kk].im));
  }
  __syncthreads();
  // ---- stage 3 (M=32)
#pragma unroll
  for (int m = 0; m < 8; ++m) {
    uint2 u = R0[sg(base3 + 4 * m)]; v0[m].re = u2h(u.x); v0[m].im = u2h(u.y);
    u = R1[sg(base3 + 4 * m)];       v1[m].re = u2h(u.x); v1[m].im = u2h(u.y);
  }
  hdft8<-1>(v0); hdft8<-1>(v1);
#pragma unroll
  for (int kk = 1; kk < 8; ++kk) {
    v0[kk] = hcmul(v0[kk], t3re[kk - 1], t3im[kk - 1]);
    v1[kk] = hcmul(v1[kk], t3re[kk - 1], t3im[kk - 1]);
  }
#pragma unroll
  for (int kk = 0; kk < 8; ++kk) {
    R0[sg(base3 + 4 * kk)] = make_uint2(h2u(v0[kk].re), h2u(v0[kk].im));
    R1[sg(base3 + 4 * kk)] = make_uint2(h2u(v1[kk].re), h2u(v1[kk].im));
  }
  __syncthreads();
  // ---- stage 4 (M=4 radix-4, thread-private quads 8t..8t+7)
#pragma unroll
  for (int kk = 0; kk < 8; ++kk) {
    uint2 u = R0[sg(8 * t + kk)]; v0[kk].re = u2h(u.x); v0[kk].im = u2h(u.y);
    u = R1[sg(8 * t + kk)];       v1[kk].re = u2h(u.x); v1[kk].im = u2h(u.y);
  }
  hdft4<-1>(v0[0], v0[1], v0[2], v0[3]); hdft4<-1>(v0[4], v0[5], v0[6], v0[7]);
  hdft4<-1>(v1[0], v1[1], v1[2], v1[3]); hdft4<-1>(v1[4], v1[5], v1[6], v1[7]);
#pragma unroll
  for (int kk = 0; kk < 8; ++kk) {
    R0[sg(8 * t + kk)] = make_uint2(h2u(v0[kk].re), h2u(v0[kk].im));
    R1[sg(8 * t + kk)] = make_uint2(h2u(v1[kk].re), h2u(v1[kk].im));
  }
  __syncthreads();
  // ---- product: P = Qf*conj(Kf), -f by digit arithmetic; fp32 accumulate
  // all 4 channels (2 per region).
  float2 acc[8];
#pragma unroll
  for (int kk = 0; kk < 8; ++kk) {
    int pos = 8 * t + kk;
    int f  = ((pos >> 8) & 7) | (((pos >> 5) & 7) << 3) | (((pos >> 2) & 7) << 6) | ((pos & 3) << 9);
    int fp = (2048 - f) & 2047;
    int pp = ((fp & 7) << 8) | (((fp >> 3) & 7) << 5) | (((fp >> 6) & 7) << 2) | ((fp >> 9) & 3);
    float sx = 0.f, sy = 0.f;
    {
      uint2 ub = R0[sg(pp)];
      __half2 bre = u2h(ub.x), bim = u2h(ub.y);
      float ar0 = __low2float(v0[kk].re),  ar1 = __high2float(v0[kk].re);
      float ai0 = __low2float(v0[kk].im),  ai1 = __high2float(v0[kk].im);
      float br0 = __low2float(bre),        br1 = __high2float(bre);
      float bi0 = __low2float(bim),        bi1 = __high2float(bim);
      sx += (br0 * ai0 + bi0 * ar0) + (br1 * ai1 + bi1 * ar1);
      sy += (ar0 * ar0 + ai0 * ai0 - br0 * br0 - bi0 * bi0)
          + (ar1 * ar1 + ai1 * ai1 - br1 * br1 - bi1 * bi1);
    }
    {
      uint2 ub = R1[sg(pp)];
      __half2 bre = u2h(ub.x), bim = u2h(ub.y);
      float ar0 = __low2float(v1[kk].re),  ar1 = __high2float(v1[kk].re);
      float ai0 = __low2float(v1[kk].im),  ai1 = __high2float(v1[kk].im);
      float br0 = __low2float(bre),        br1 = __high2float(bre);
      float bi0 = __low2float(bim),        bi1 = __high2float(bim);
      sx += (br0 * ai0 + bi0 * ar0) + (br1 * ai1 + bi1 * ar1);
      sy += (ar0 * ar0 + ai0 * ai0 - br0 * br0 - bi0 * bi0)
          + (ar1 * ar1 + ai1 * ai1 - br1 * br1 - bi1 * bi1);
    }
    acc[kk] = make_float2(0.5f * sx, 0.25f * sy);
  }
  __syncthreads();                        // product reads of R0/R1 complete
  // park fp32 sums into region 0, then coalesced 256-wide store.
  {
    float2* pk0 = (float2*)dbuf;
#pragma unroll
    for (int kk = 0; kk < 8; ++kk) pk0[sg(8 * t + kk)] = acc[kk];
  }
  __syncthreads();
  {
    const float2* pk0 = (const float2*)dbuf;
    float2* prow = part + (size_t)l * L_;   // LOGICAL block id
#pragma unroll
    for (int m = 0; m < 8; ++m) {
      int p = t + 256 * m;
      prow[p] = pk0[sg(p)];
    }
  }
}

// ---------- kernel R: sum 128 partial rows -> S[b][p] ----------
__global__ __launch_bounds__(256) void reduce_S_kernel(
    const float2* __restrict__ part, float2* __restrict__ S) {
  int idx = blockIdx.x * 256 + threadIdx.x;   // 0..32767 = [b][p]
  int p = idx & 2047;
  int b = idx >> 11;
  float2 s = make_float2(0.f, 0.f);
#pragma unroll 4
  for (int i = 0; i < 128; ++i) {
    float2 vv = part[(size_t)(b * 128 + i) * L_ + p];
    s.x += vv.x; s.y += vv.y;
  }
  S[idx] = s;
}

// ---------- kernel I: mirrored DIT inverse (digit-reversed in, natural out) ----------
__global__ __launch_bounds__(256) void ifft_kernel(
    const float2* __restrict__ S, float* __restrict__ mv) {
  __shared__ float2 buf[2176];
  int t = threadIdx.x, b = blockIdx.x;
  int j2 = t & 31, j3 = t & 3;
  float2 tw1[7], tw2[7], tw3[7];
  {
    float2 w1 = cis(6.283185307179586f * (float)t  / 2048.0f);
    float2 w2 = cis(6.283185307179586f * (float)j2 / 256.0f);
    float2 w3 = cis(6.283185307179586f * (float)j3 / 32.0f);
    tw1[0] = w1; tw2[0] = w2; tw3[0] = w3;
#pragma unroll
    for (int kk = 1; kk < 7; ++kk) {
      tw1[kk] = cmul(tw1[kk - 1], w1);
      tw2[kk] = cmul(tw2[kk - 1], w2);
      tw3[kk] = cmul(tw3[kk - 1], w3);
    }
  }
  int base2 = (t >> 5) * 256 + j2;
  int base3 = (t >> 2) * 32 + j3;
  // stage A: M=4 DFT (no twiddle), quads 8t..8t+7
  float2 u[8];
  {
    const float4* rp = (const float4*)(S + (size_t)b * L_);
#pragma unroll
    for (int m = 0; m < 4; ++m) {
      float4 f = rp[4 * t + m];
      u[2 * m]     = make_float2(f.x, f.y);
      u[2 * m + 1] = make_float2(f.z, f.w);
    }
  }
  dft4<1>(u[0], u[1], u[2], u[3]);
  dft4<1>(u[4], u[5], u[6], u[7]);
#pragma unroll
  for (int kk = 0; kk < 8; ++kk) buf[sg(8 * t + kk)] = u[kk];
  __syncthreads();
  // stage B: M=32
  float2 v[8];
#pragma unroll
  for (int kk = 0; kk < 8; ++kk) v[kk] = buf[sg(base3 + 4 * kk)];
#pragma unroll
  for (int kk = 1; kk < 8; ++kk) v[kk] = cmul(v[kk], tw3[kk - 1]);
  dft8<1>(v);
  __syncthreads();
#pragma unroll
  for (int m = 0; m < 8; ++m) buf[sg(base3 + 4 * m)] = v[m];
  __syncthreads();
  // stage C: M=256
#pragma unroll
  for (int kk = 0; kk < 8; ++kk) v[kk] = buf[sg(base2 + 32 * kk)];
#pragma unroll
  for (int kk = 1; kk < 8; ++kk) v[kk] = cmul(v[kk], tw2[kk - 1]);
  dft8<1>(v);
  __syncthreads();
#pragma unroll
  for (int m = 0; m < 8; ++m) buf[sg(base2 + 32 * m)] = v[m];
  __syncthreads();
  // stage D: M=2048 -> natural order
#pragma unroll
  for (int kk = 0; kk < 8; ++kk) v[kk] = buf[sg(t + 256 * kk)];
#pragma unroll
  for (int kk = 1; kk < 8; ++kk) v[kk] = cmul(v[kk], tw1[kk - 1]);
  dft8<1>(v);
  const float scale = 1.0f / (2048.0f * 512.0f);  // 1/N * mean over H*E
#pragma unroll
  for (int m = 0; m < 8; ++m) mv[b * L_ + t + 256 * m] = v[m].x * scale;
}

// ---------- kernel K: batch-mean top-7 + per-batch softmax weights ----------
__global__ __launch_bounds__(256) void topk_kernel(
    const float* __restrict__ mv, int* __restrict__ topk, float* __restrict__ wts) {
  __shared__ float av[2048];
  __shared__ float rv[256];
  __shared__ int   ri[256];
  __shared__ int   sidx[K_];
  int tid = threadIdx.x;
  for (int d = tid; d < 2048; d += 256) {
    float s = 0.f;
#pragma unroll
    for (int b = 0; b < B_; ++b) s += mv[b * L_ + d];
    av[d] = s;
  }
  __syncthreads();
  for (int kk = 0; kk < K_; ++kk) {
    float bv = -INFINITY; int bi = 0;
    for (int d = tid; d < 2048; d += 256) {
      float vv = av[d];
      if (vv > bv) { bv = vv; bi = d; }
    }
    rv[tid] = bv; ri[tid] = bi;
    __syncthreads();
    for (int off = 128; off > 0; off >>= 1) {
      if (tid < off) {
        float v2 = rv[tid + off]; int i2 = ri[tid + off];
        if (v2 > rv[tid] || (v2 == rv[tid] && i2 < ri[tid])) { rv[tid] = v2; ri[tid] = i2; }
      }
      __syncthreads();
    }
    if (tid == 0) { sidx[kk] = ri[0]; av[ri[0]] = -INFINITY; }
    __syncthreads();
  }
  if (tid < K_) topk[tid] = sidx[tid];
  if (tid < B_) {
    float xk[K_], m = -INFINITY;
#pragma unroll
    for (int kk = 0; kk < K_; ++kk) { xk[kk] = mv[tid * L_ + sidx[kk]]; m = fmaxf(m, xk[kk]); }
    float s = 0.f;
#pragma unroll
    for (int kk = 0; kk < K_; ++kk) { xk[kk] = expf(xk[kk] - m); s += xk[kk]; }
#pragma unroll
    for (int kk = 0; kk < K_; ++kk) wts[tid * K_ + kk] = xk[kk] / s;
  }
}

// ---------- kernel G: out[b,t,h,e] = sum_k w[b,k] * v[b,(t+d_k)%L,h,e] ----------
__global__ __launch_bounds__(256) void aggregate_kernel(
    const float4* __restrict__ v4, const int* __restrict__ topk,
    const float* __restrict__ wts, float4* __restrict__ out4) {
  __shared__ int   sidx[K_];
  __shared__ float sw[B_][K_];
  int tid = threadIdx.x;
  if (tid < K_) sidx[tid] = topk[tid];
  if (tid < B_ * K_) sw[tid / K_][tid % K_] = wts[tid];
  __syncthreads();
  int idx = blockIdx.x * 256 + tid;
  int c4  = idx & 127;
  int row = idx >> 7;
  int t   = row & (L_ - 1);
  int b   = row >> 11;
  float4 acc = make_float4(0.f, 0.f, 0.f, 0.f);
#pragma unroll
  for (int kk = 0; kk < K_; ++kk) {
    int s = t + sidx[kk];
    if (s >= L_) s -= L_;
    float w = sw[b][kk];
    float4 val = v4[((size_t)(b * L_ + s) << 7) + c4];
    acc.x += w * val.x; acc.y += w * val.y;
    acc.z += w * val.z; acc.w += w * val.w;
  }
  out4[idx] = acc;
}

extern "C" void kernel_launch(void* const* d_in, const int* in_sizes, int n_in,
                              void* d_out, int out_size, void* d_ws, size_t ws_size,
                              hipStream_t stream) {
  const float* q = (const float*)d_in[0];
  const float* k = (const float*)d_in[1];
  const float* v = (const float*)d_in[2];
  float* out = (float*)d_out;

  char* ws = (char*)d_ws;
  float4* z    = (float4*)(ws + Z_OFF);
  float2* part = (float2*)(ws + PART_OFF);
  float2* S    = (float2*)(ws + S_OFF);
  float*  mv   = (float*) (ws + MV_OFF);
  int*    topk = (int*)   (ws + TK_OFF);
  float*  wts  = (float*) (ws + W_OFF);

  pack_kernel<<<2048, 256, 0, stream>>>(q, k, z);
  fft_corr_kernel<<<B_ * 128, 256, 2 * RS_ * sizeof(uint2), stream>>>(z, part);
  reduce_S_kernel<<<(B_ * L_) / 256, 256, 0, stream>>>(part, S);
  ifft_kernel<<<B_, 256, 0, stream>>>(S, mv);
  topk_kernel<<<1, 256, 0, stream>>>(mv, topk, wts);
  aggregate_kernel<<<(B_ * L_ * H_ * E_ / 4) / 256, 256, 0, stream>>>(
      (const float4*)v, topk, wts, (float4*)out);
}

// Round 17
// 149.847 us; speedup vs baseline: 1.0684x; 1.0684x over previous
//
#include <hip/hip_runtime.h>
#include <hip/hip_bf16.h>
#include <hip/hip_fp16.h>
#include <math.h>

// AutoCorrelation (Autoformer). B=16, L=2048, H=8, E=64, fp32.
// Round 17: r16 retry -- identical to validated r14 config (153us best) plus
// non-temporal `out` stores in aggregate, now via a native clang vector type
// (HIP's float4 class is rejected by __builtin_nontemporal_store).

#define B_ 16
#define L_ 2048
#define H_ 8
#define E_ 64
#define K_ 7
#define RS_ 2178          // region stride in uint2 (8B) units; sg(2047)=2174 < RS_

typedef float nfloat4 __attribute__((ext_vector_type(4)));  // native vec for NT store

// ---------- workspace layout ----------
#define Z_OFF    0ull                              // fp16 slabs: 1024 x 64KB = 64 MiB
#define PART_OFF 67108864ull                       // float2[2048][2048] = 32 MiB
#define S_OFF    (PART_OFF + 33554432ull)          // float2[16][2048] = 256 KiB
#define MV_OFF   (S_OFF + 262144ull)               // float [B][L]
#define TK_OFF   (MV_OFF + 131072ull)              // int[7]
#define W_OFF    (TK_OFF + 64ull)                  // float[16][7]

// ---------- fp32 complex helpers (ifft/twiddle gen) ----------
__device__ __forceinline__ float2 cadd(float2 a, float2 b) { return make_float2(a.x + b.x, a.y + b.y); }
__device__ __forceinline__ float2 csub(float2 a, float2 b) { return make_float2(a.x - b.x, a.y - b.y); }
__device__ __forceinline__ float2 cmul(float2 a, float2 b) {
  return make_float2(fmaf(a.x, b.x, -a.y * b.y), fmaf(a.x, b.y, a.y * b.x));
}
__device__ __forceinline__ float2 cis(float ang) { float s, c; sincosf(ang, &s, &c); return make_float2(c, s); }

template<int S> __device__ __forceinline__ float2 rot90(float2 z) {
  return (S < 0) ? make_float2(z.y, -z.x) : make_float2(-z.y, z.x);
}
template<int S> __device__ __forceinline__ void dft4(float2& a, float2& b, float2& c, float2& d) {
  float2 t0 = cadd(a, c), t1 = csub(a, c), t2 = cadd(b, d), t3 = rot90<S>(csub(b, d));
  a = cadd(t0, t2); c = csub(t0, t2); b = cadd(t1, t3); d = csub(t1, t3);
}
template<int S> __device__ __forceinline__ void dft8(float2 v[8]) {
  const float RT = 0.70710678118654752f;
  const float SR = (S < 0) ? -RT : RT;
  float2 a0 = cadd(v[0], v[4]), a1 = cadd(v[1], v[5]), a2 = cadd(v[2], v[6]), a3 = cadd(v[3], v[7]);
  float2 b0 = csub(v[0], v[4]), b1 = csub(v[1], v[5]), b2 = csub(v[2], v[6]), b3 = csub(v[3], v[7]);
  b1 = cmul(b1, make_float2(RT, SR));
  b2 = rot90<S>(b2);
  b3 = cmul(b3, make_float2(-RT, SR));
  dft4<S>(a0, a1, a2, a3);
  dft4<S>(b0, b1, b2, b3);
  v[0] = a0; v[2] = a1; v[4] = a2; v[6] = a3;
  v[1] = b0; v[3] = b1; v[5] = b2; v[7] = b3;
}
// padded index: +1 element per 16 (<=2-way across all stage patterns)
__device__ __forceinline__ int sg(int e) { return e + (e >> 4); }

// ---------- packed-fp16 complex (channel pair per __half2 lane-slot) ----------
struct hc { __half2 re, im; };
__device__ __forceinline__ hc hcadd(hc a, hc b) { return { __hadd2(a.re, b.re), __hadd2(a.im, b.im) }; }
__device__ __forceinline__ hc hcsub(hc a, hc b) { return { __hsub2(a.re, b.re), __hsub2(a.im, b.im) }; }
template<int S> __device__ __forceinline__ hc hrot90(hc z) {       // *(-i) fwd
  hc r; if (S < 0) { r.re = z.im; r.im = __hneg2(z.re); } else { r.re = __hneg2(z.im); r.im = z.re; }
  return r;
}
__device__ __forceinline__ hc hcmul(hc v, __half2 wre, __half2 wim) {
  hc r;
  r.re = __hsub2(__hmul2(v.re, wre), __hmul2(v.im, wim));
  r.im = __hfma2(v.re, wim, __hmul2(v.im, wre));
  return r;
}
template<int S> __device__ __forceinline__ void hdft4(hc& a, hc& b, hc& c, hc& d) {
  hc t0 = hcadd(a, c), t1 = hcsub(a, c), t2 = hcadd(b, d), t3 = hrot90<S>(hcsub(b, d));
  a = hcadd(t0, t2); c = hcsub(t0, t2); b = hcadd(t1, t3); d = hcsub(t1, t3);
}
template<int S> __device__ __forceinline__ void hdft8(hc v[8]) {
  const float RT = 0.70710678118654752f;
  __half2 rt  = __float2half2_rn(RT);
  __half2 sr  = __float2half2_rn((S < 0) ? -RT : RT);
  __half2 nrt = __float2half2_rn(-RT);
  hc a0 = hcadd(v[0], v[4]), a1 = hcadd(v[1], v[5]), a2 = hcadd(v[2], v[6]), a3 = hcadd(v[3], v[7]);
  hc b0 = hcsub(v[0], v[4]), b1 = hcsub(v[1], v[5]), b2 = hcsub(v[2], v[6]), b3 = hcsub(v[3], v[7]);
  b1 = hcmul(b1, rt, sr);
  b2 = hrot90<S>(b2);
  b3 = hcmul(b3, nrt, sr);
  hdft4<S>(a0, a1, a2, a3);
  hdft4<S>(b0, b1, b2, b3);
  v[0] = a0; v[2] = a1; v[4] = a2; v[6] = a3;
  v[1] = b0; v[3] = b1; v[5] = b2; v[7] = b3;
}
__device__ __forceinline__ __half2 u2h(unsigned u) { return __builtin_bit_cast(__half2, u); }
__device__ __forceinline__ unsigned h2u(__half2 h) { return __builtin_bit_cast(unsigned, h); }

// ---------- kernel P: barrier-free pack q,k -> pair-packed fp16 slabs ----------
// Block (b, tile) = 512 threads = 8 waves, zero LDS. Each wave transposes 8
// independent 8x8-f4 subtiles via lane-permute: read c-major (8x128B runs),
// __shfl lane swap (r,c)->(c,r), write r-major (8x128B runs). Slab layout
// identical to r11-r14: f4 at (cq,j) = [re01,im01,re23,im23].
__global__ __launch_bounds__(512) void pack_kernel(
    const float* __restrict__ q, const float* __restrict__ k,
    float4* __restrict__ z) {
  int tid = threadIdx.x;
  int l = blockIdx.x;                     // b*64 + tl
  int tl = l & 63, b = l >> 6;
  size_t rowbase = ((size_t)b * L_ + tl * 32) * 512;   // floats
  const float4* q4 = (const float4*)(q + rowbase);
  const float4* k4 = (const float4*)(k + rowbase);
  float4* slab = z + (size_t)l * 4096;
  int w = tid >> 6;                       // wave 0..7
  int lane = tid & 63;
  int r = lane >> 3, c = lane & 7;        // read roles
  int srcLane = ((lane & 7) << 3) | (lane >> 3);
#pragma unroll
  for (int i = 0; i < 8; ++i) {
    int s = w * 8 + i;                    // subtile 0..63
    int tr = s & 3, cc = s >> 2;          // tau-octet, cq-octet
    int ridx = (tr * 8 + r) * 128 + cc * 8 + c;
    float4 qv = q4[ridx];
    float4 kv = k4[ridx];
    float4 pk;
    ((__half2*)&pk)[0] = __float22half2_rn(make_float2(qv.x, qv.y));  // re01
    ((__half2*)&pk)[1] = __float22half2_rn(make_float2(kv.x, kv.y));  // im01
    ((__half2*)&pk)[2] = __float22half2_rn(make_float2(qv.z, qv.w));  // re23
    ((__half2*)&pk)[3] = __float22half2_rn(make_float2(kv.z, kv.w));  // im23
    // 8x8 transpose across lanes: dest lane (8c+r) pulls from lane (8r+c)
    float4 tp;
    tp.x = __shfl(pk.x, srcLane, 64);
    tp.y = __shfl(pk.y, srcLane, 64);
    tp.z = __shfl(pk.z, srcLane, 64);
    tp.w = __shfl(pk.w, srcLane, 64);
    // lane now holds element (tau = tr*8 + (lane&7), cq = cc*8 + (lane>>3))
    slab[(cc * 8 + (lane >> 3)) * 32 + tr * 8 + (lane & 7)] = tp;
  }
}

// ---------- kernel F: packed-fp16 radix-8/8/8/4 DIF FFT + freq product ----------
// Block (b, cg): channels 4cg..4cg+3 as 2 packed pairs processed TOGETHER
// (dual register sets, one barrier per stage). 256 threads; 2 LDS regions of
// RS_ uint2. Staging reads 512B-contiguous slab runs (the r14-validated
// fast path). Digit-reversed storage pos=256k1+32k2+4k3+k4, f=k1+8k2+64k3+512k4.
__global__ __launch_bounds__(256, 4) void fft_corr_kernel(
    const float4* __restrict__ z, float2* __restrict__ part) {
  extern __shared__ uint2 dbuf[];         // 2 regions x RS_ uint2 = 34848 B
  int t = threadIdx.x;
  int j2 = t & 31, j3 = t & 3;
  int l = blockIdx.x;                     // b*128 + cg
  int cg = l & 127, b = l >> 7;
  const float4* zb = z + (size_t)b * 64 * 4096;

  // ---- staging: 64 tiles x 32 j of cq=cg -> 512B contiguous runs
#pragma unroll
  for (int it = 0; it < 8; ++it) {
    int m = it * 256 + t;
    int tl = m >> 5, j = m & 31;
    float4 pk = zb[(size_t)tl * 4096 + cg * 32 + j];
    int sp = sg(tl * 32 + j);
    dbuf[sp]       = make_uint2(__float_as_uint(pk.x), __float_as_uint(pk.y));
    dbuf[RS_ + sp] = make_uint2(__float_as_uint(pk.z), __float_as_uint(pk.w));
  }

  // twiddles: fp32 iterative chains -> broadcast half2
  __half2 t1re[7], t1im[7], t2re[7], t2im[7], t3re[7], t3im[7];
  {
    float2 w1 = cis(-6.283185307179586f * (float)t  / 2048.0f);
    float2 w2 = cis(-6.283185307179586f * (float)j2 / 256.0f);
    float2 w3 = cis(-6.283185307179586f * (float)j3 / 32.0f);
    float2 a1 = w1, a2 = w2, a3 = w3;
#pragma unroll
    for (int kk = 0; kk < 7; ++kk) {
      t1re[kk] = __float2half2_rn(a1.x); t1im[kk] = __float2half2_rn(a1.y);
      t2re[kk] = __float2half2_rn(a2.x); t2im[kk] = __float2half2_rn(a2.y);
      t3re[kk] = __float2half2_rn(a3.x); t3im[kk] = __float2half2_rn(a3.y);
      a1 = cmul(a1, w1); a2 = cmul(a2, w2); a3 = cmul(a3, w3);
    }
  }
  int base2 = (t >> 5) * 256 + j2;
  int base3 = (t >> 2) * 32 + j3;
  uint2* R0 = dbuf;
  uint2* R1 = dbuf + RS_;
  hc v0[8], v1[8];
  __syncthreads();                        // staging visible

  // ---- stage 1 (M=2048), both regions, in-place per thread
#pragma unroll
  for (int m = 0; m < 8; ++m) {
    uint2 u = R0[sg(t + 256 * m)]; v0[m].re = u2h(u.x); v0[m].im = u2h(u.y);
    u = R1[sg(t + 256 * m)];       v1[m].re = u2h(u.x); v1[m].im = u2h(u.y);
  }
  hdft8<-1>(v0); hdft8<-1>(v1);
#pragma unroll
  for (int kk = 1; kk < 8; ++kk) {
    v0[kk] = hcmul(v0[kk], t1re[kk - 1], t1im[kk - 1]);
    v1[kk] = hcmul(v1[kk], t1re[kk - 1], t1im[kk - 1]);
  }
#pragma unroll
  for (int kk = 0; kk < 8; ++kk) {
    R0[sg(t + 256 * kk)] = make_uint2(h2u(v0[kk].re), h2u(v0[kk].im));
    R1[sg(t + 256 * kk)] = make_uint2(h2u(v1[kk].re), h2u(v1[kk].im));
  }
  __syncthreads();
  // ---- stage 2 (M=256)
#pragma unroll
  for (int m = 0; m < 8; ++m) {
    uint2 u = R0[sg(base2 + 32 * m)]; v0[m].re = u2h(u.x); v0[m].im = u2h(u.y);
    u = R1[sg(base2 + 32 * m)];       v1[m].re = u2h(u.x); v1[m].im = u2h(u.y);
  }
  hdft8<-1>(v0); hdft8<-1>(v1);
#pragma unroll
  for (int kk = 1; kk < 8; ++kk) {
    v0[kk] = hcmul(v0[kk], t2re[kk - 1], t2im[kk - 1]);
    v1[kk] = hcmul(v1[kk], t2re[kk - 1], t2im[kk - 1]);
  }
#pragma unroll
  for (int kk = 0; kk < 8; ++kk) {
    R0[sg(base2 + 32 * kk)] = make_uint2(h2u(v0[kk].re), h2u(v0[kk].im));
    R1[sg(base2 + 32 * kk)] = make_uint2(h2u(v1[kk].re), h2u(v1[kk].im));
  }
  __syncthreads();
  // ---- stage 3 (M=32)
#pragma unroll
  for (int m = 0; m < 8; ++m) {
    uint2 u = R0[sg(base3 + 4 * m)]; v0[m].re = u2h(u.x); v0[m].im = u2h(u.y);
    u = R1[sg(base3 + 4 * m)];       v1[m].re = u2h(u.x); v1[m].im = u2h(u.y);
  }
  hdft8<-1>(v0); hdft8<-1>(v1);
#pragma unroll
  for (int kk = 1; kk < 8; ++kk) {
    v0[kk] = hcmul(v0[kk], t3re[kk - 1], t3im[kk - 1]);
    v1[kk] = hcmul(v1[kk], t3re[kk - 1], t3im[kk - 1]);
  }
#pragma unroll
  for (int kk = 0; kk < 8; ++kk) {
    R0[sg(base3 + 4 * kk)] = make_uint2(h2u(v0[kk].re), h2u(v0[kk].im));
    R1[sg(base3 + 4 * kk)] = make_uint2(h2u(v1[kk].re), h2u(v1[kk].im));
  }
  __syncthreads();
  // ---- stage 4 (M=4 radix-4, thread-private quads 8t..8t+7)
#pragma unroll
  for (int kk = 0; kk < 8; ++kk) {
    uint2 u = R0[sg(8 * t + kk)]; v0[kk].re = u2h(u.x); v0[kk].im = u2h(u.y);
    u = R1[sg(8 * t + kk)];       v1[kk].re = u2h(u.x); v1[kk].im = u2h(u.y);
  }
  hdft4<-1>(v0[0], v0[1], v0[2], v0[3]); hdft4<-1>(v0[4], v0[5], v0[6], v0[7]);
  hdft4<-1>(v1[0], v1[1], v1[2], v1[3]); hdft4<-1>(v1[4], v1[5], v1[6], v1[7]);
#pragma unroll
  for (int kk = 0; kk < 8; ++kk) {
    R0[sg(8 * t + kk)] = make_uint2(h2u(v0[kk].re), h2u(v0[kk].im));
    R1[sg(8 * t + kk)] = make_uint2(h2u(v1[kk].re), h2u(v1[kk].im));
  }
  __syncthreads();
  // ---- product: P = Qf*conj(Kf), -f by digit arithmetic; fp32 accumulate
  // all 4 channels (2 per region).
  float2 acc[8];
#pragma unroll
  for (int kk = 0; kk < 8; ++kk) {
    int pos = 8 * t + kk;
    int f  = ((pos >> 8) & 7) | (((pos >> 5) & 7) << 3) | (((pos >> 2) & 7) << 6) | ((pos & 3) << 9);
    int fp = (2048 - f) & 2047;
    int pp = ((fp & 7) << 8) | (((fp >> 3) & 7) << 5) | (((fp >> 6) & 7) << 2) | ((fp >> 9) & 3);
    float sx = 0.f, sy = 0.f;
    {
      uint2 ub = R0[sg(pp)];
      __half2 bre = u2h(ub.x), bim = u2h(ub.y);
      float ar0 = __low2float(v0[kk].re),  ar1 = __high2float(v0[kk].re);
      float ai0 = __low2float(v0[kk].im),  ai1 = __high2float(v0[kk].im);
      float br0 = __low2float(bre),        br1 = __high2float(bre);
      float bi0 = __low2float(bim),        bi1 = __high2float(bim);
      sx += (br0 * ai0 + bi0 * ar0) + (br1 * ai1 + bi1 * ar1);
      sy += (ar0 * ar0 + ai0 * ai0 - br0 * br0 - bi0 * bi0)
          + (ar1 * ar1 + ai1 * ai1 - br1 * br1 - bi1 * bi1);
    }
    {
      uint2 ub = R1[sg(pp)];
      __half2 bre = u2h(ub.x), bim = u2h(ub.y);
      float ar0 = __low2float(v1[kk].re),  ar1 = __high2float(v1[kk].re);
      float ai0 = __low2float(v1[kk].im),  ai1 = __high2float(v1[kk].im);
      float br0 = __low2float(bre),        br1 = __high2float(bre);
      float bi0 = __low2float(bim),        bi1 = __high2float(bim);
      sx += (br0 * ai0 + bi0 * ar0) + (br1 * ai1 + bi1 * ar1);
      sy += (ar0 * ar0 + ai0 * ai0 - br0 * br0 - bi0 * bi0)
          + (ar1 * ar1 + ai1 * ai1 - br1 * br1 - bi1 * bi1);
    }
    acc[kk] = make_float2(0.5f * sx, 0.25f * sy);
  }
  __syncthreads();                        // product reads of R0/R1 complete
  // park fp32 sums into region 0, then coalesced 256-wide store.
  {
    float2* pk0 = (float2*)dbuf;
#pragma unroll
    for (int kk = 0; kk < 8; ++kk) pk0[sg(8 * t + kk)] = acc[kk];
  }
  __syncthreads();
  {
    const float2* pk0 = (const float2*)dbuf;
    float2* prow = part + (size_t)l * L_;
#pragma unroll
    for (int m = 0; m < 8; ++m) {
      int p = t + 256 * m;
      prow[p] = pk0[sg(p)];
    }
  }
}

// ---------- kernel R: sum 128 partial rows -> S[b][p] ----------
__global__ __launch_bounds__(256) void reduce_S_kernel(
    const float2* __restrict__ part, float2* __restrict__ S) {
  int idx = blockIdx.x * 256 + threadIdx.x;   // 0..32767 = [b][p]
  int p = idx & 2047;
  int b = idx >> 11;
  float2 s = make_float2(0.f, 0.f);
#pragma unroll 4
  for (int i = 0; i < 128; ++i) {
    float2 vv = part[(size_t)(b * 128 + i) * L_ + p];
    s.x += vv.x; s.y += vv.y;
  }
  S[idx] = s;
}

// ---------- kernel I: mirrored DIT inverse (digit-reversed in, natural out) ----------
__global__ __launch_bounds__(256) void ifft_kernel(
    const float2* __restrict__ S, float* __restrict__ mv) {
  __shared__ float2 buf[2176];
  int t = threadIdx.x, b = blockIdx.x;
  int j2 = t & 31, j3 = t & 3;
  float2 tw1[7], tw2[7], tw3[7];
  {
    float2 w1 = cis(6.283185307179586f * (float)t  / 2048.0f);
    float2 w2 = cis(6.283185307179586f * (float)j2 / 256.0f);
    float2 w3 = cis(6.283185307179586f * (float)j3 / 32.0f);
    tw1[0] = w1; tw2[0] = w2; tw3[0] = w3;
#pragma unroll
    for (int kk = 1; kk < 7; ++kk) {
      tw1[kk] = cmul(tw1[kk - 1], w1);
      tw2[kk] = cmul(tw2[kk - 1], w2);
      tw3[kk] = cmul(tw3[kk - 1], w3);
    }
  }
  int base2 = (t >> 5) * 256 + j2;
  int base3 = (t >> 2) * 32 + j3;
  // stage A: M=4 DFT (no twiddle), quads 8t..8t+7
  float2 u[8];
  {
    const float4* rp = (const float4*)(S + (size_t)b * L_);
#pragma unroll
    for (int m = 0; m < 4; ++m) {
      float4 f = rp[4 * t + m];
      u[2 * m]     = make_float2(f.x, f.y);
      u[2 * m + 1] = make_float2(f.z, f.w);
    }
  }
  dft4<1>(u[0], u[1], u[2], u[3]);
  dft4<1>(u[4], u[5], u[6], u[7]);
#pragma unroll
  for (int kk = 0; kk < 8; ++kk) buf[sg(8 * t + kk)] = u[kk];
  __syncthreads();
  // stage B: M=32
  float2 v[8];
#pragma unroll
  for (int kk = 0; kk < 8; ++kk) v[kk] = buf[sg(base3 + 4 * kk)];
#pragma unroll
  for (int kk = 1; kk < 8; ++kk) v[kk] = cmul(v[kk], tw3[kk - 1]);
  dft8<1>(v);
  __syncthreads();
#pragma unroll
  for (int m = 0; m < 8; ++m) buf[sg(base3 + 4 * m)] = v[m];
  __syncthreads();
  // stage C: M=256
#pragma unroll
  for (int kk = 0; kk < 8; ++kk) v[kk] = buf[sg(base2 + 32 * kk)];
#pragma unroll
  for (int kk = 1; kk < 8; ++kk) v[kk] = cmul(v[kk], tw2[kk - 1]);
  dft8<1>(v);
  __syncthreads();
#pragma unroll
  for (int m = 0; m < 8; ++m) buf[sg(base2 + 32 * m)] = v[m];
  __syncthreads();
  // stage D: M=2048 -> natural order
#pragma unroll
  for (int kk = 0; kk < 8; ++kk) v[kk] = buf[sg(t + 256 * kk)];
#pragma unroll
  for (int kk = 1; kk < 8; ++kk) v[kk] = cmul(v[kk], tw1[kk - 1]);
  dft8<1>(v);
  const float scale = 1.0f / (2048.0f * 512.0f);  // 1/N * mean over H*E
#pragma unroll
  for (int m = 0; m < 8; ++m) mv[b * L_ + t + 256 * m] = v[m].x * scale;
}

// ---------- kernel K: batch-mean top-7 + per-batch softmax weights ----------
__global__ __launch_bounds__(256) void topk_kernel(
    const float* __restrict__ mv, int* __restrict__ topk, float* __restrict__ wts) {
  __shared__ float av[2048];
  __shared__ float rv[256];
  __shared__ int   ri[256];
  __shared__ int   sidx[K_];
  int tid = threadIdx.x;
  for (int d = tid; d < 2048; d += 256) {
    float s = 0.f;
#pragma unroll
    for (int b = 0; b < B_; ++b) s += mv[b * L_ + d];
    av[d] = s;
  }
  __syncthreads();
  for (int kk = 0; kk < K_; ++kk) {
    float bv = -INFINITY; int bi = 0;
    for (int d = tid; d < 2048; d += 256) {
      float vv = av[d];
      if (vv > bv) { bv = vv; bi = d; }
    }
    rv[tid] = bv; ri[tid] = bi;
    __syncthreads();
    for (int off = 128; off > 0; off >>= 1) {
      if (tid < off) {
        float v2 = rv[tid + off]; int i2 = ri[tid + off];
        if (v2 > rv[tid] || (v2 == rv[tid] && i2 < ri[tid])) { rv[tid] = v2; ri[tid] = i2; }
      }
      __syncthreads();
    }
    if (tid == 0) { sidx[kk] = ri[0]; av[ri[0]] = -INFINITY; }
    __syncthreads();
  }
  if (tid < K_) topk[tid] = sidx[tid];
  if (tid < B_) {
    float xk[K_], m = -INFINITY;
#pragma unroll
    for (int kk = 0; kk < K_; ++kk) { xk[kk] = mv[tid * L_ + sidx[kk]]; m = fmaxf(m, xk[kk]); }
    float s = 0.f;
#pragma unroll
    for (int kk = 0; kk < K_; ++kk) { xk[kk] = expf(xk[kk] - m); s += xk[kk]; }
#pragma unroll
    for (int kk = 0; kk < K_; ++kk) wts[tid * K_ + kk] = xk[kk] / s;
  }
}

// ---------- kernel G: out[b,t,h,e] = sum_k w[b,k] * v[b,(t+d_k)%L,h,e] ----------
// out is write-once/never-re-read -> non-temporal stores keep it out of L3
// (per-replay touched set ~364MB > 256MB L3; this frees ~67MB for v/q/k).
__global__ __launch_bounds__(256) void aggregate_kernel(
    const float4* __restrict__ v4, const int* __restrict__ topk,
    const float* __restrict__ wts, nfloat4* __restrict__ out4) {
  __shared__ int   sidx[K_];
  __shared__ float sw[B_][K_];
  int tid = threadIdx.x;
  if (tid < K_) sidx[tid] = topk[tid];
  if (tid < B_ * K_) sw[tid / K_][tid % K_] = wts[tid];
  __syncthreads();
  int idx = blockIdx.x * 256 + tid;
  int c4  = idx & 127;
  int row = idx >> 7;
  int t   = row & (L_ - 1);
  int b   = row >> 11;
  float4 acc = make_float4(0.f, 0.f, 0.f, 0.f);
#pragma unroll
  for (int kk = 0; kk < K_; ++kk) {
    int s = t + sidx[kk];
    if (s >= L_) s -= L_;
    float w = sw[b][kk];
    float4 val = v4[((size_t)(b * L_ + s) << 7) + c4];
    acc.x += w * val.x; acc.y += w * val.y;
    acc.z += w * val.z; acc.w += w * val.w;
  }
  nfloat4 nv = { acc.x, acc.y, acc.z, acc.w };
  __builtin_nontemporal_store(nv, &out4[idx]);
}

extern "C" void kernel_launch(void* const* d_in, const int* in_sizes, int n_in,
                              void* d_out, int out_size, void* d_ws, size_t ws_size,
                              hipStream_t stream) {
  const float* q = (const float*)d_in[0];
  const float* k = (const float*)d_in[1];
  const float* v = (const float*)d_in[2];
  float* out = (float*)d_out;

  char* ws = (char*)d_ws;
  float4* z    = (float4*)(ws + Z_OFF);
  float2* part = (float2*)(ws + PART_OFF);
  float2* S    = (float2*)(ws + S_OFF);
  float*  mv   = (float*) (ws + MV_OFF);
  int*    topk = (int*)   (ws + TK_OFF);
  float*  wts  = (float*) (ws + W_OFF);

  pack_kernel<<<B_ * 64, 512, 0, stream>>>(q, k, z);
  fft_corr_kernel<<<B_ * 128, 256, 2 * RS_ * sizeof(uint2), stream>>>(z, part);
  reduce_S_kernel<<<(B_ * L_) / 256, 256, 0, stream>>>(part, S);
  ifft_kernel<<<B_, 256, 0, stream>>>(S, mv);
  topk_kernel<<<1, 256, 0, stream>>>(mv, topk, wts);
  aggregate_kernel<<<(B_ * L_ * H_ * E_ / 4) / 256, 256, 0, stream>>>(
      (const float4*)v, topk, wts, (nfloat4*)out);
}